// Round 2
// baseline (195.074 us; speedup 1.0000x reference)
//
#include <hip/hip_runtime.h>

// CT parallel-beam pixel-driven back-projection. Static geometry.
// Two-kernel design:
//   prep_kernel (R16): one block per (group g, batch b). Each thread computes
//     bins i..i+3 of BOTH fused opposing-view pair arrays —
//     A = views (g, g+360), B = (g+180, g+540) — entry (D,S) fp16 with
//     S[i] = fwd[i] + rev[735-i], D = S[i+1]-S[i], stored INTERLEAVED:
//     entry j is 8 B {A(D,S), B(D,S)}.
//   backproject_dma_kernel: staging = pure global_load_lds DMA (16 B) into
//     a 4-deep LDS ring; issue(p+1) BEFORE groups(p), barrier AFTER (R15).
//   R17 (this round): R16 proved LDS gather is BYTE-RATE limited (~42 B/cyc:
//     b32 gather 6.0 cyc, b64 gather 12.3 cyc — same B/cyc, conflicts not
//     the limit). The vm (TA/L1) pipe is idle. Split the gather across both
//     pipes: 5 of 8 visits/sub read LDS (ds_read_b64), 3 of 8 read the SAME
//     entries straight from ws via global_load_dwordx2 (L1/L2-resident,
//     12.3 KB working set/iter). Pipes run concurrently ->
//     LDS time/iter 3148 -> ~1970 cyc, vm ~1500 cyc, VALU ~1000 cyc.
// Symmetries (verified R7-R12): view quad {v,v+180,v+360,v+540} x pixel
// rotation orbit; 4 visits u = C+-g1, C+-g2 per group serve 16 pixel-views.
// Fallback: if ws_size < needed, launch the proven R12 kernel (161 us).
#define BATCH 8
#define NVIEW 720
#define NPAIR 360
#define NGRP  180
#define NDET  736
#define IMGH  512
#define IMGW  512

#define DANG_F  ((float)(6.283185307179586 / 720.0))
#define RATIO_F ((float)(0.006641 / 0.0066))
#define UCENTER ((float)((NDET - 1) * 0.5))

#define PADDET 768   // padded entries per group (8 B each; 1024B DMA tiling)
#define ITER_BYTES 12288  // 2 groups x 768 entries x 8 B per iteration
#define SUB_BYTES  6144   // one group's interleaved array
#define WS_BYTES ((size_t)BATCH * NGRP * PADDET * 8)

typedef float  v2f __attribute__((ext_vector_type(2)));
typedef __fp16 v2h __attribute__((ext_vector_type(2)));
typedef __fp16 v4h __attribute__((ext_vector_type(4)));

// ---------------- prep kernel (interleaved A/B) ----------------
// grid (180, 8), block 192 (threads 0..183 active). Group g: pairA rows
// (g, g+360), pairB rows (g+180, g+540) — all in [0,720) of batch b.
// Thread owns bins i..i+3 of both arrays. Overshoot: fwd[i+4] at i=732
// reads next row elem 0 (fwd rows <= 359, next row exists in-batch);
// rev[-1] reads prev row last elem (rev rows >= 360). Both land only in
// bin 735's D, never read (i0 <= 731). Pad [736,768) unwritten, DMA'd
// but never read.
__global__ __launch_bounds__(192) void prep_kernel(
    const float* __restrict__ proj, v2h* __restrict__ ws)
{
    const int t = threadIdx.x;
    if (t >= 184) return;
    const int g = blockIdx.x;
    const int b = blockIdx.y;
    const int i = 4 * t;
    const float* __restrict__ fA = proj + ((size_t)b * NVIEW + g) * NDET;
    const float* __restrict__ rA = fA + (size_t)NPAIR * NDET;   // g+360
    const float* __restrict__ fB = fA + (size_t)NGRP * NDET;    // g+180
    const float* __restrict__ rB = fB + (size_t)NPAIR * NDET;   // g+540
    const float4 fa4 = *(const float4*)(fA + i);
    const float  fa1 = fA[i + 4];
    const float4 ra4 = *(const float4*)(rA + (732 - i));  // taps i..i+3=(w,z,y,x)
    const float  ra1 = rA[731 - i];                       // tap i+4
    const float4 fb4 = *(const float4*)(fB + i);
    const float  fb1 = fB[i + 4];
    const float4 rb4 = *(const float4*)(rB + (732 - i));
    const float  rb1 = rB[731 - i];
    const float sa0 = fa4.x + ra4.w;
    const float sa1 = fa4.y + ra4.z;
    const float sa2 = fa4.z + ra4.y;
    const float sa3 = fa4.w + ra4.x;
    const float sa4 = fa1 + ra1;
    const float sb0 = fb4.x + rb4.w;
    const float sb1 = fb4.y + rb4.z;
    const float sb2 = fb4.z + rb4.y;
    const float sb3 = fb4.w + rb4.x;
    const float sb4 = fb1 + rb1;
    const v2h nA0 = __builtin_amdgcn_cvt_pkrtz(sa1 - sa0, sa0);   // (D, S)
    const v2h nA1 = __builtin_amdgcn_cvt_pkrtz(sa2 - sa1, sa1);
    const v2h nA2 = __builtin_amdgcn_cvt_pkrtz(sa3 - sa2, sa2);
    const v2h nA3 = __builtin_amdgcn_cvt_pkrtz(sa4 - sa3, sa3);
    const v2h nB0 = __builtin_amdgcn_cvt_pkrtz(sb1 - sb0, sb0);
    const v2h nB1 = __builtin_amdgcn_cvt_pkrtz(sb2 - sb1, sb1);
    const v2h nB2 = __builtin_amdgcn_cvt_pkrtz(sb3 - sb2, sb2);
    const v2h nB3 = __builtin_amdgcn_cvt_pkrtz(sb4 - sb3, sb3);
    struct alignas(16) H8 { v2h a0, b0, a1, b1; };  // entries j, j+1
    v2h* __restrict__ dst =
        ws + ((size_t)b * NGRP + g) * (2 * PADDET) + 2 * i;
    *(H8*)(dst)     = H8{nA0, nB0, nA1, nB1};
    *(H8*)(dst + 4) = H8{nA2, nB2, nA3, nB3};
}

// One u value from LDS: single ds_read_b64 pulls interleaved {A(D,S),B(D,S)}.
__device__ __forceinline__ void visit(const v2h* __restrict__ L,
                                      float u, float& accA, float& accB) {
    const int   i0 = (int)u;                      // u in [3.9, 731.1] always
    const float fr = __builtin_amdgcn_fractf(u);
    const v2h wv = __builtin_amdgcn_cvt_pkrtz(fr, 1.0f);
    const v4h AB = *(const v4h*)(L + 2 * i0);     // ds_read_b64, 8B-aligned
    const v2h A = {AB.x, AB.y};
    const v2h B = {AB.z, AB.w};
    accA = __builtin_amdgcn_fdot2(A, wv, accA, false);   // S + fr*D
    accB = __builtin_amdgcn_fdot2(B, wv, accB, false);
}

// R17: same visit but gathering straight from ws (global_load_dwordx2,
// L1/L2-resident 12.3 KB/iter working set) — runs on the vm pipe,
// concurrent with the LDS pipe.
__device__ __forceinline__ void gvisit(const v4h* __restrict__ G,
                                       float u, float& accA, float& accB) {
    const int   i0 = (int)u;
    const float fr = __builtin_amdgcn_fractf(u);
    const v2h wv = __builtin_amdgcn_cvt_pkrtz(fr, 1.0f);
    const v4h AB = G[i0];                         // global_load_dwordx2
    const v2h A = {AB.x, AB.y};
    const v2h B = {AB.z, AB.w};
    accA = __builtin_amdgcn_fdot2(A, wv, accA, false);
    accB = __builtin_amdgcn_fdot2(B, wv, accB, false);
}

// ---------------- main kernel (DMA path) ----------------
// 512 threads = 8 waves; wave = one h row of the top-left quadrant, lanes =
// 64 consecutive w; thread owns two rotation orbits (w0, w0+128).
// Grid 512 = exactly 2 blocks/CU. Iteration p stages groups (2p, 2p+1):
// 12288 B = 12 slices of 1024 B (64 lanes x 16 B); wave w takes slice w,
// waves 0..3 also take slice 8+w (wave-uniform branch).
// Pipeline (R15): issue(p+1) -> groups(p) -> __syncthreads. The barrier's
// vmcnt(0) drain waits on a DMA aged by groups(p) (~2000+ cyc) -> free.
// groups(p)'s slot p&3 was drained by iteration p-1's end barrier.
// Ring safety: issue(p+1) writes slot (p+1)&3 while groups(p) reads p&3;
// prior content of slot (p+1)&3 (iter p-3) was last read in groups(p-3),
// sealed by that iteration's end barrier, which all waves have passed.
// Bounds check proven unnecessary: |g1|,|g2| <= 363.6 < 367.5.
// NOTE (R17): the end-barrier's vmcnt(0) drain also waits on this
// iteration's gvisit loads — they are consumed by fdot2 before it anyway.
__global__ __launch_bounds__(512, 4) void backproject_dma_kernel(
    const v2h* __restrict__ ws, float* __restrict__ out)
{
    __shared__ alignas(16) v2h lds4[4][2 * 2 * PADDET];  // 4 x 12288 B ring
    __shared__ v2f cs[NGRP];

    const int tid  = threadIdx.x;
    const int wave = tid >> 6;
    const int lane = tid & 63;

    if (tid < NGRP) {
        float s, c;
        sincosf((float)tid * DANG_F, &s, &c);
        cs[tid] = (v2f){c * RATIO_F, s * RATIO_F};   // sealed by 1st barrier
    }

    const int b  = blockIdx.z;
    const int h  = (int)blockIdx.y * 8 + wave;           // [0, 256)
    const int w0 = (int)blockIdx.x * 64 + lane;          // [0, 128)

    const float px = (float)w0 - (float)(IMGW - 1) * 0.5f;
    const float py = (float)(IMGH - 1) * 0.5f - (float)h;

    const char* __restrict__ wsb =
        (const char*)(ws + (size_t)b * NGRP * 2 * PADDET);

    float a0 = 0.f, a1 = 0.f, a2 = 0.f, a3 = 0.f;
    float b0 = 0.f, b1 = 0.f, b2 = 0.f, b3 = 0.f;

    auto issue = [&](int p) {
        const char* g0 = wsb + (size_t)p * ITER_BYTES;
        char* l0 = (char*)&lds4[p & 3][0];
        __builtin_amdgcn_global_load_lds(
            (const __attribute__((address_space(1))) void*)
                (g0 + wave * 1024 + lane * 16),
            (__attribute__((address_space(3))) void*)(l0 + wave * 1024),
            16, 0, 0);
        if (wave < 4) {
            const int s = 8 + wave;
            __builtin_amdgcn_global_load_lds(
                (const __attribute__((address_space(1))) void*)
                    (g0 + s * 1024 + lane * 16),
                (__attribute__((address_space(3))) void*)(l0 + s * 1024),
                16, 0, 0);
        }
    };

    auto groups = [&](int p) {
        const v2h* __restrict__ L4 = &lds4[p & 3][0];
#pragma unroll
        for (int sub = 0; sub < 2; ++sub) {
            const v2h* __restrict__ L = L4 + sub * (2 * PADDET);
            const v4h* __restrict__ G =
                (const v4h*)(wsb + (size_t)p * ITER_BYTES + sub * SUB_BYTES);
            const v2f t = cs[2 * p + sub];
            // (g1, g2) = px*(c, -s) + py*(s, c)  -- packed fp32
            const v2f m1 = {t.x, -t.y};
            const v2f m2 = {t.y, t.x};
            const v2f pxv = {px, px};
            const v2f pyv = {py, py};
            const v2f gvec = __builtin_elementwise_fma(pxv, m1, pyv * m2);
            const v2f cc = {UCENTER, UCENTER};
            const v2f up = cc + gvec;      // rep0 (C+g1, C+g2)
            const v2f um = cc - gvec;      // rep0 (C-g1, C-g2)
            const v2f dd = {128.0f, 128.0f};
            const v2f dm = dd * m1;        // 128*(cx, -sy)
            const v2f vp = up + dm;        // rep1
            const v2f vm = um - dm;        // rep1

            visit (L, up.x, a0, a1);   // +g1: A->q0, B->q1
            visit (L, um.x, a2, a3);   // -g1: A->q2, B->q3
            visit (L, up.y, a3, a0);   // +g2: A->q3, B->q0
            visit (L, um.y, a1, a2);   // -g2: A->q1, B->q2
            gvisit(G, vp.x, b0, b1);   // vm-pipe (L1 gather)
            gvisit(G, vm.x, b2, b3);   // vm-pipe
            gvisit(G, vp.y, b3, b0);   // vm-pipe
            visit (L, vm.y, b1, b2);
        }
    };

    issue(0);
    __syncthreads();   // drains issue(0) (once) + seals cs[]
    for (int p = 0; p < 90; ++p) {
        if (p + 1 < 90) issue(p + 1);
        groups(p);
        if (p + 1 < 90) __syncthreads();   // drain aged DMA; RW separation
    }

    float* __restrict__ o = out + (size_t)b * IMGH * IMGW;
    const int hm  = (IMGH - 1) - h;
    const int w1  = w0 + 128;
    const int wm0 = (IMGW - 1) - w0;
    const int wm1 = (IMGW - 1) - w1;
    o[h   * IMGW + w0 ] = a0 * DANG_F;
    o[wm0 * IMGW + h  ] = a1 * DANG_F;
    o[hm  * IMGW + wm0] = a2 * DANG_F;
    o[w0  * IMGW + hm ] = a3 * DANG_F;
    o[h   * IMGW + w1 ] = b0 * DANG_F;
    o[wm1 * IMGW + h  ] = b1 * DANG_F;
    o[hm  * IMGW + wm1] = b2 * DANG_F;
    o[w1  * IMGW + hm ] = b3 * DANG_F;
}

// ---------------- fallback (R12, proven 161 us) ----------------
struct Stage { float4 f4, r4; float f1, r1; };

__device__ __forceinline__ void fb_load(const float* __restrict__ sino,
                                        int k, int t, Stage& S) {
    if (t < 368) {
        const int p  = (t >= 184);
        const int i  = 4 * (t - 184 * p);
        const int vf = k + 180 * p;
        const float* __restrict__ fwd = sino + vf * NDET;
        const float* __restrict__ rev = sino + (vf + NPAIR) * NDET;
        S.f4 = *(const float4*)(fwd + i);
        S.f1 = fwd[i + 4];
        S.r4 = *(const float4*)(rev + (732 - i));
        S.r1 = rev[731 - i];
    }
}

__device__ __forceinline__ void fb_write(v2h* __restrict__ L, int t,
                                         const Stage& S) {
    if (t < 368) {
        const int p = (t >= 184);
        const int i = 4 * (t - 184 * p);
        const float s0 = S.f4.x + S.r4.w;
        const float s1 = S.f4.y + S.r4.z;
        const float s2 = S.f4.z + S.r4.y;
        const float s3 = S.f4.w + S.r4.x;
        const float s4 = S.f1 + S.r1;
        const v2h n0 = __builtin_amdgcn_cvt_pkrtz(s1 - s0, s0);
        const v2h n1 = __builtin_amdgcn_cvt_pkrtz(s2 - s1, s1);
        const v2h n2 = __builtin_amdgcn_cvt_pkrtz(s3 - s2, s2);
        const v2h n3 = __builtin_amdgcn_cvt_pkrtz(s4 - s3, s3);
        struct alignas(16) H4 { v2h a, b, c, d; };
        *(H4*)(L + p * NDET + i) = H4{n0, n1, n2, n3};
    }
}

__device__ __forceinline__ void fb_visit(const v2h* __restrict__ L,
                                         float u, float& accA, float& accB) {
    const int   i0 = (int)u;
    const float fr = __builtin_amdgcn_fractf(u);
    const v2h wv = __builtin_amdgcn_cvt_pkrtz(fr, 1.0f);
    const v2h A = L[i0];
    const v2h B = L[i0 + NDET];
    accA = __builtin_amdgcn_fdot2(A, wv, accA, false);
    accB = __builtin_amdgcn_fdot2(B, wv, accB, false);
}

__global__ __launch_bounds__(512, 4) void backproject_fb_kernel(
    const float* __restrict__ proj, float* __restrict__ out)
{
    __shared__ alignas(16) v2h lds[2][2][2 * NDET];
    __shared__ v2f cs[NGRP];

    const int tid = threadIdx.x;
    if (tid < NGRP) {
        float s, c;
        sincosf((float)tid * DANG_F, &s, &c);
        cs[tid] = (v2f){c * RATIO_F, s * RATIO_F};
    }

    const int b    = blockIdx.z;
    const int lane = tid & 63;
    const int h    = (int)blockIdx.y * 8 + (tid >> 6);
    const int w0   = (int)blockIdx.x * 64 + lane;

    const float px = (float)w0 - (float)(IMGW - 1) * 0.5f;
    const float py = (float)(IMGH - 1) * 0.5f - (float)h;

    const float* __restrict__ sino = proj + (size_t)b * NVIEW * NDET;

    float a0 = 0.f, a1 = 0.f, a2 = 0.f, a3 = 0.f;
    float b0 = 0.f, b1 = 0.f, b2 = 0.f, b3 = 0.f;

    Stage s0 = {}, s1 = {};
    fb_load(sino, 0, tid, s0);
    fb_load(sino, 1, tid, s1);
    fb_write(lds[0][0], tid, s0);
    fb_write(lds[0][1], tid, s1);
    fb_load(sino, 2, tid, s0);
    fb_load(sino, 3, tid, s1);
    __syncthreads();

    for (int gg = 0; gg < NGRP; gg += 2) {
        const int buf = (gg >> 1) & 1;
#pragma unroll
        for (int sub = 0; sub < 2; ++sub) {
            const v2h* __restrict__ L = lds[buf][sub];
            const v2f t = cs[gg + sub];
            const v2f m1 = {t.x, -t.y};
            const v2f m2 = {t.y, t.x};
            const v2f pxv = {px, px};
            const v2f pyv = {py, py};
            const v2f gvec = __builtin_elementwise_fma(pxv, m1, pyv * m2);
            const v2f cc = {UCENTER, UCENTER};
            const v2f up = cc + gvec;
            const v2f um = cc - gvec;
            const v2f dd = {128.0f, 128.0f};
            const v2f dm = dd * m1;
            const v2f vp = up + dm;
            const v2f vm = um - dm;

            fb_visit(L, up.x, a0, a1);
            fb_visit(L, um.x, a2, a3);
            fb_visit(L, up.y, a3, a0);
            fb_visit(L, um.y, a1, a2);
            fb_visit(L, vp.x, b0, b1);
            fb_visit(L, vm.x, b2, b3);
            fb_visit(L, vp.y, b3, b0);
            fb_visit(L, vm.y, b1, b2);
        }
        if (gg < NGRP - 2) {
            fb_write(lds[buf ^ 1][0], tid, s0);
            fb_write(lds[buf ^ 1][1], tid, s1);
            if (gg < NGRP - 4) {
                fb_load(sino, gg + 4, tid, s0);
                fb_load(sino, gg + 5, tid, s1);
            }
            __syncthreads();
        }
    }

    float* __restrict__ o = out + (size_t)b * IMGH * IMGW;
    const int hm  = (IMGH - 1) - h;
    const int w1  = w0 + 128;
    const int wm0 = (IMGW - 1) - w0;
    const int wm1 = (IMGW - 1) - w1;
    o[h   * IMGW + w0 ] = a0 * DANG_F;
    o[wm0 * IMGW + h  ] = a1 * DANG_F;
    o[hm  * IMGW + wm0] = a2 * DANG_F;
    o[w0  * IMGW + hm ] = a3 * DANG_F;
    o[h   * IMGW + w1 ] = b0 * DANG_F;
    o[wm1 * IMGW + h  ] = b1 * DANG_F;
    o[hm  * IMGW + wm1] = b2 * DANG_F;
    o[w1  * IMGW + hm ] = b3 * DANG_F;
}

extern "C" void kernel_launch(void* const* d_in, const int* in_sizes, int n_in,
                              void* d_out, int out_size, void* d_ws, size_t ws_size,
                              hipStream_t stream) {
    const float* proj = (const float*)d_in[0];
    float* out = (float*)d_out;

    if (ws_size >= WS_BYTES) {
        v2h* ws = (v2h*)d_ws;
        prep_kernel<<<dim3(NGRP, BATCH), 192, 0, stream>>>(proj, ws);
        backproject_dma_kernel<<<dim3(2, 32, BATCH), 512, 0, stream>>>(ws, out);
    } else {
        backproject_fb_kernel<<<dim3(2, 32, BATCH), 512, 0, stream>>>(proj, out);
    }
}

// Round 3
// 144.694 us; speedup vs baseline: 1.3482x; 1.3482x over previous
//
#include <hip/hip_runtime.h>

// CT parallel-beam pixel-driven back-projection. Static geometry.
// R18: mirror-pair restructure. Groups pair under theta -> 90deg-theta
// (g <-> 180-g): u(transposed-pixel-orbit, 180-g) == u(pixel-orbit, g).
// ws entry = 16 B {A_g(D,S), B_g(D,S), A_m(D,S), B_m(D,S)} so ONE
// ds_read_b128 gather (measured ~12 cyc, same as b64: DS wide reads are
// instruction-limited, not byte-limited) feeds 4 fdot2: group g for the
// thread's own rotation orbit + group m for the transposed orbit.
// LDS gathers/thread: 1440 (R16) -> 728. Same fdot2 count, same DMA ring.
//
// Thread basing: fundamental domain of the dihedral-8 group.
//   lane (h,w), h in [0,256), w in [0,128):
//     w <  h: P1 = (h, w)            (lower-triangle rep)
//     w >  h: P1 = (255-h, 255-w)    (remap; W < H strict)
//     w == h: diagonal thread: P1 = (d,d), second base P2b = (255-d,255-d)
// Accumulator banks (16 f32): A[4] (vis1-4 slots 1,2), X[4] (vis1-4 slots
// 3,4), B[4] (vis5-8 slots 1,2), Y[4] (vis5-8 slots 3,4). Inner loop is
// LANE-UNIFORM; normal-vs-diagonal differs only in per-lane coords
// (P2 = swap(px,py) vs base2 coords) and a write-time X/Y select:
//   normal: out[R^j(P1)] = A+Y;  out[R^j(transpose P1)] = B+X
//   diag:   out[R^j(P1)] = A+X;  out[R^j(256+d,256+d)]  = B+Y
// Groups {0,90} are self-mirrored -> special final iteration (iter 89):
// uniform path for normal lanes (A/X banks, double-target visits at
// theta=0 and theta=45), small divergent block for the 128 diag lanes.
// Visit tables derived from u(pi,gamma)=C+pi_x*c+pi_y*s and B-array-serves-
// R(pi); verified numerically (pixels (0,0),(250,225),(10,10) vs groups).
// Fallback: if ws_size < needed, launch the proven R12 kernel (161 us).
#define BATCH 8
#define NVIEW 720
#define NPAIR 360
#define NGRP  180
#define NDET  736
#define IMGH  512
#define IMGW  512

#define DANG_F  ((float)(6.283185307179586 / 720.0))
#define RATIO_F ((float)(0.006641 / 0.0066))
#define UCENTER ((float)((NDET - 1) * 0.5))

#define PADDET 768        // entries per pair-iter (16 B each)
#define NITER  90         // 89 mirror pairs + 1 self-pair {0,90}
#define ITER_BYTES 12288  // 768 x 16 B
#define WS_BYTES ((size_t)BATCH * NITER * PADDET * 16)

typedef float  v2f __attribute__((ext_vector_type(2)));
typedef __fp16 v2h __attribute__((ext_vector_type(2)));
typedef __fp16 v8h __attribute__((ext_vector_type(8)));

struct alignas(16) E16 { v2h ag, bg, am, bm; };

// ---------------- prep kernel ----------------
// grid (90, 8), block 192 (threads 0..183). Pair p: (g,m) = p<89 ?
// (p+1, 179-p) : (0, 90). Entry j: fused (D,S) fp16 for the 4 sub-arrays,
// S[j] = fwd[j] + rev[735-j], D = S[j+1]-S[j]. Overshoot taps (fwd[i+4] at
// i=732, rev[-1]) land only in entry 735's D, never read (i0 <= 731);
// they stay within the batch's proj rows. Pad [736,768) unwritten.
__device__ __forceinline__ void fuse5(const float* __restrict__ fwd,
                                      const float* __restrict__ rev,
                                      int i, float s[5]) {
    const float4 f4 = *(const float4*)(fwd + i);
    const float  f1 = fwd[i + 4];
    const float4 r4 = *(const float4*)(rev + (732 - i));  // taps i..i+3=(w,z,y,x)
    const float  r1 = rev[731 - i];                       // tap i+4
    s[0] = f4.x + r4.w; s[1] = f4.y + r4.z; s[2] = f4.z + r4.y;
    s[3] = f4.w + r4.x; s[4] = f1 + r1;
}

__global__ __launch_bounds__(192) void prep_kernel(
    const float* __restrict__ proj, E16* __restrict__ ws)
{
    const int t = threadIdx.x;
    if (t >= 184) return;
    const int p = blockIdx.x;
    const int b = blockIdx.y;
    const int g = (p < 89) ? p + 1   : 0;
    const int m = (p < 89) ? 179 - p : 90;
    const int i = 4 * t;
    const float* __restrict__ base = proj + (size_t)b * NVIEW * NDET;
    float sAg[5], sBg[5], sAm[5], sBm[5];
    fuse5(base + (size_t)g * NDET,         base + (size_t)(g + 360) * NDET, i, sAg);
    fuse5(base + (size_t)(g + 180) * NDET, base + (size_t)(g + 540) * NDET, i, sBg);
    fuse5(base + (size_t)m * NDET,         base + (size_t)(m + 360) * NDET, i, sAm);
    fuse5(base + (size_t)(m + 180) * NDET, base + (size_t)(m + 540) * NDET, i, sBm);
    E16* __restrict__ dst = ws + ((size_t)b * NITER + p) * PADDET + i;
#pragma unroll
    for (int k = 0; k < 4; ++k) {
        E16 e;
        e.ag = __builtin_amdgcn_cvt_pkrtz(sAg[k + 1] - sAg[k], sAg[k]);
        e.bg = __builtin_amdgcn_cvt_pkrtz(sBg[k + 1] - sBg[k], sBg[k]);
        e.am = __builtin_amdgcn_cvt_pkrtz(sAm[k + 1] - sAm[k], sAm[k]);
        e.bm = __builtin_amdgcn_cvt_pkrtz(sBm[k + 1] - sBm[k], sBm[k]);
        dst[k] = e;
    }
}

// One b128 gather -> 4 fdot2 into 4 distinct accumulators.
#define VIS(Lp, u, r0, r1, r2, r3) do {                                      \
    const float uu_ = (u);                                                   \
    const int   ii_ = (int)uu_;                                              \
    const v2h wv_ = __builtin_amdgcn_cvt_pkrtz(                              \
        __builtin_amdgcn_fractf(uu_), 1.0f);                                 \
    const v8h E_ = (Lp)[ii_];                                                \
    r0 = __builtin_amdgcn_fdot2((v2h){E_[0], E_[1]}, wv_, r0, false);        \
    r1 = __builtin_amdgcn_fdot2((v2h){E_[2], E_[3]}, wv_, r1, false);        \
    r2 = __builtin_amdgcn_fdot2((v2h){E_[4], E_[5]}, wv_, r2, false);        \
    r3 = __builtin_amdgcn_fdot2((v2h){E_[6], E_[7]}, wv_, r3, false);        \
} while (0)

// Iter-89 visit: half-pair at elems [O,O+1] -> p0 AND p1; [O+2,O+3] -> q0,q1.
#define VIS2(Lp, O, u, p0, p1, q0, q1) do {                                  \
    const float uu_ = (u);                                                   \
    const int   ii_ = (int)uu_;                                              \
    const v2h wv_ = __builtin_amdgcn_cvt_pkrtz(                              \
        __builtin_amdgcn_fractf(uu_), 1.0f);                                 \
    const v8h E_ = (Lp)[ii_];                                                \
    const v2h ha_ = {E_[(O)], E_[(O) + 1]};                                  \
    const v2h hb_ = {E_[(O) + 2], E_[(O) + 3]};                              \
    p0 = __builtin_amdgcn_fdot2(ha_, wv_, p0, false);                        \
    p1 = __builtin_amdgcn_fdot2(ha_, wv_, p1, false);                        \
    q0 = __builtin_amdgcn_fdot2(hb_, wv_, q0, false);                        \
    q1 = __builtin_amdgcn_fdot2(hb_, wv_, q1, false);                        \
} while (0)

// Iter-89 diag: one target per half.
#define VIS1(Lp, O, u, p0, q0) do {                                          \
    const float uu_ = (u);                                                   \
    const int   ii_ = (int)uu_;                                              \
    const v2h wv_ = __builtin_amdgcn_cvt_pkrtz(                              \
        __builtin_amdgcn_fractf(uu_), 1.0f);                                 \
    const v8h E_ = (Lp)[ii_];                                                \
    p0 = __builtin_amdgcn_fdot2((v2h){E_[(O)], E_[(O) + 1]}, wv_, p0, false);\
    q0 = __builtin_amdgcn_fdot2((v2h){E_[(O) + 2], E_[(O) + 3]}, wv_, q0,    \
                                false);                                      \
} while (0)

// ---------------- main kernel (DMA path) ----------------
// 512 threads = 8 waves; grid (2, 32, BATCH) = 2 blocks/CU. Iteration p
// stages its 12288 B pair-block: 12 slices of 1024 B, wave w slice w,
// waves 0..3 also slice 8+w. Pipeline (R15): issue(p+1) -> visits(p) ->
// __syncthreads (vmcnt(0) drain waits on an aged DMA -> free). 4-slot ring;
// safety as before. |g1|,|g2| <= 363.6 < 367.5 -> i0 in [3,731], +1 tap
// <= 732 < 736. R(row,col) = (511-col, row); centered R(x,y) = (-y, x).
__global__ __launch_bounds__(512, 4) void backproject_dma_kernel(
    const v8h* __restrict__ ws, float* __restrict__ out)
{
    __shared__ alignas(16) v8h lds4[4][PADDET];  // 4 x 12288 B ring
    __shared__ v2f cs[NGRP];

    const int tid  = threadIdx.x;
    const int wave = tid >> 6;
    const int lane = tid & 63;

    if (tid < NGRP) {
        float s, c;
        sincosf((float)tid * DANG_F, &s, &c);
        cs[tid] = (v2f){c * RATIO_F, s * RATIO_F};   // sealed by 1st barrier
    }

    const int b = blockIdx.z;
    const int h = (int)blockIdx.y * 8 + wave;            // [0, 256)
    const int w = (int)blockIdx.x * 64 + lane;           // [0, 128)

    const bool dg = (w == h);                            // diagonal lane
    const bool rm = (w > h);                             // remapped lane
    const int  H  = rm ? 255 - h : h;
    const int  W  = rm ? 255 - w : w;

    const float px  = (float)W - 255.5f;
    const float py  = 255.5f - (float)H;
    // P2: normal/remap -> swap (k-addresses); diag -> base2 = (255-d,255-d).
    const float px2 = dg ? (-0.5f - (float)W) : py;
    const float py2 = dg ? ( 0.5f + (float)H) : px;

    const char* __restrict__ wsb =
        (const char*)(ws + (size_t)b * NITER * PADDET);

    float A0 = 0.f, A1 = 0.f, A2 = 0.f, A3 = 0.f;
    float B0 = 0.f, B1 = 0.f, B2 = 0.f, B3 = 0.f;
    float X0 = 0.f, X1 = 0.f, X2 = 0.f, X3 = 0.f;
    float Y0 = 0.f, Y1 = 0.f, Y2 = 0.f, Y3 = 0.f;

    auto issue = [&](int p) {
        const char* g0 = wsb + (size_t)p * ITER_BYTES;
        char* l0 = (char*)&lds4[p & 3][0];
        __builtin_amdgcn_global_load_lds(
            (const __attribute__((address_space(1))) void*)
                (g0 + wave * 1024 + lane * 16),
            (__attribute__((address_space(3))) void*)(l0 + wave * 1024),
            16, 0, 0);
        if (wave < 4) {
            const int s = 8 + wave;
            __builtin_amdgcn_global_load_lds(
                (const __attribute__((address_space(1))) void*)
                    (g0 + s * 1024 + lane * 16),
                (__attribute__((address_space(3))) void*)(l0 + s * 1024),
                16, 0, 0);
        }
    };

    issue(0);
    __syncthreads();   // drains issue(0) + seals cs[]

    const v2f cc = {UCENTER, UCENTER};
    for (int p = 0; p < NITER - 1; ++p) {
        issue(p + 1);
        {
            const v8h* __restrict__ L = &lds4[p & 3][0];
            const v2f t  = cs[p + 1];                // group g = p+1
            const v2f m1 = {t.x, -t.y};
            const v2f m2 = {t.y, t.x};
            // (g1,g2) for P1; (g1b,g2b) for P2 — all at theta_g.
            const v2f gA = __builtin_elementwise_fma(
                (v2f){px, px}, m1, (v2f){py, py} * m2);
            const v2f gB = __builtin_elementwise_fma(
                (v2f){px2, px2}, m1, (v2f){py2, py2} * m2);
            const v2f upA = cc + gA, umA = cc - gA;
            const v2f upB = cc + gB, umB = cc - gB;
            VIS(L, upA.x, A0, A1, X2, X3);   // C+g1
            VIS(L, umA.x, A2, A3, X0, X1);   // C-g1
            VIS(L, upA.y, A3, A0, X3, X0);   // C+g2
            VIS(L, umA.y, A1, A2, X1, X2);   // C-g2
            VIS(L, upB.x, B2, B3, Y0, Y1);   // C+g1b
            VIS(L, umB.x, B0, B1, Y2, Y3);   // C-g1b
            VIS(L, upB.y, B1, B2, Y1, Y2);   // C+g2b
            VIS(L, umB.y, B3, B0, Y3, Y0);   // C-g2b
        }
        __syncthreads();
    }

    // -------- iter 89: self-mirrored groups {0, 90} (slot 89&3 = 1) -----
    {
        const v8h* __restrict__ L = &lds4[(NITER - 1) & 3][0];
        const v2f t0 = cs[0], t45 = cs[90];
        if (!dg) {
            // theta=0 (halves 0,1 = A0/B0 arrays), P1 addresses; each value
            // serves own-orbit AND transposed-orbit pixel (same column/row).
            const float g1 = px * t0.x + py * t0.y;
            const float g2 = -px * t0.y + py * t0.x;
            VIS2(L, 0, UCENTER + g1, A0, X1, A1, X2);
            VIS2(L, 0, UCENTER - g1, A2, X3, A3, X0);
            VIS2(L, 0, UCENTER + g2, A3, X2, A0, X3);
            VIS2(L, 0, UCENTER - g2, A1, X0, A2, X1);
            // theta=45 (halves 4..7 = A90/B90 arrays).
            const float h1 = px * t45.x + py * t45.y;
            const float h2 = -px * t45.y + py * t45.x;
            VIS2(L, 4, UCENTER + h1, A0, X2, A1, X3);
            VIS2(L, 4, UCENTER - h1, A2, X0, A3, X1);
            VIS2(L, 4, UCENTER + h2, A3, X3, A0, X0);
            VIS2(L, 4, UCENTER - h2, A1, X1, A2, X2);
        } else {
            // Diagonal lanes: base1 = (d,d) into A-bank; base2 into B-bank
            // (relabeled b_j = R^(j+2)(base2)).
            const float g1  = px * t0.x + py * t0.y;    // theta0, base1
            const float g1b = px2 * t0.x + py2 * t0.y;  // theta0, base2
            VIS2(L, 0, UCENTER + g1,  A0, A1, A1, A2);
            VIS2(L, 0, UCENTER - g1,  A2, A3, A0, A3);
            VIS2(L, 0, UCENTER + g1b, B2, B3, B3, B0);
            VIS2(L, 0, UCENTER - g1b, B0, B1, B2, B1);
            // theta=45: P1-orbit sums pi_x+pi_y in {0, +-2px}; base2 same.
            {   // u = UCENTER: serves base1 {a0,a2}/{a1,a3} and base2.
                const v2h wv_ = __builtin_amdgcn_cvt_pkrtz(0.5f, 1.0f);
                const v8h E_ = L[(int)UCENTER];
                const v2h ha_ = {E_[4], E_[5]};
                const v2h hb_ = {E_[6], E_[7]};
                A0 = __builtin_amdgcn_fdot2(ha_, wv_, A0, false);
                A2 = __builtin_amdgcn_fdot2(ha_, wv_, A2, false);
                B2 = __builtin_amdgcn_fdot2(ha_, wv_, B2, false);
                B0 = __builtin_amdgcn_fdot2(ha_, wv_, B0, false);
                A1 = __builtin_amdgcn_fdot2(hb_, wv_, A1, false);
                A3 = __builtin_amdgcn_fdot2(hb_, wv_, A3, false);
                B3 = __builtin_amdgcn_fdot2(hb_, wv_, B3, false);
                B1 = __builtin_amdgcn_fdot2(hb_, wv_, B1, false);
            }
            const float e1 = (px + px) * t45.x;
            const float e2 = (px2 + px2) * t45.x;
            VIS1(L, 4, UCENTER + e1, A1, A2);
            VIS1(L, 4, UCENTER - e1, A3, A0);
            VIS1(L, 4, UCENTER + e2, B3, B0);
            VIS1(L, 4, UCENTER - e2, B1, B2);
        }
    }

    // -------- write: 8 pixels, two R-orbits --------
    const float aE0 = dg ? X0 : Y0, aE1 = dg ? X1 : Y1;
    const float aE2 = dg ? X2 : Y2, aE3 = dg ? X3 : Y3;
    const float bE0 = dg ? Y0 : X0, bE1 = dg ? Y1 : X1;
    const float bE2 = dg ? Y2 : X2, bE3 = dg ? Y3 : X3;
    const float a0 = (A0 + aE0) * DANG_F, a1 = (A1 + aE1) * DANG_F;
    const float a2 = (A2 + aE2) * DANG_F, a3 = (A3 + aE3) * DANG_F;
    const float b0 = (B0 + bE0) * DANG_F, b1 = (B1 + bE1) * DANG_F;
    const float b2 = (B2 + bE2) * DANG_F, b3 = (B3 + bE3) * DANG_F;

    float* __restrict__ o = out + (size_t)b * IMGH * IMGW;
    const int Qr = dg ? 256 + H : W;
    const int Qc = dg ? 256 + W : H;
    o[H * IMGW + W]                         = a0;
    o[(511 - W) * IMGW + H]                 = a1;
    o[(511 - H) * IMGW + (511 - W)]         = a2;
    o[W * IMGW + (511 - H)]                 = a3;
    o[Qr * IMGW + Qc]                       = b0;
    o[(511 - Qc) * IMGW + Qr]               = b1;
    o[(511 - Qr) * IMGW + (511 - Qc)]       = b2;
    o[Qc * IMGW + (511 - Qr)]               = b3;
}

// ---------------- fallback (R12, proven 161 us) ----------------
struct Stage { float4 f4, r4; float f1, r1; };

__device__ __forceinline__ void fb_load(const float* __restrict__ sino,
                                        int k, int t, Stage& S) {
    if (t < 368) {
        const int p  = (t >= 184);
        const int i  = 4 * (t - 184 * p);
        const int vf = k + 180 * p;
        const float* __restrict__ fwd = sino + vf * NDET;
        const float* __restrict__ rev = sino + (vf + NPAIR) * NDET;
        S.f4 = *(const float4*)(fwd + i);
        S.f1 = fwd[i + 4];
        S.r4 = *(const float4*)(rev + (732 - i));
        S.r1 = rev[731 - i];
    }
}

__device__ __forceinline__ void fb_write(v2h* __restrict__ L, int t,
                                         const Stage& S) {
    if (t < 368) {
        const int p = (t >= 184);
        const int i = 4 * (t - 184 * p);
        const float s0 = S.f4.x + S.r4.w;
        const float s1 = S.f4.y + S.r4.z;
        const float s2 = S.f4.z + S.r4.y;
        const float s3 = S.f4.w + S.r4.x;
        const float s4 = S.f1 + S.r1;
        const v2h n0 = __builtin_amdgcn_cvt_pkrtz(s1 - s0, s0);
        const v2h n1 = __builtin_amdgcn_cvt_pkrtz(s2 - s1, s1);
        const v2h n2 = __builtin_amdgcn_cvt_pkrtz(s3 - s2, s2);
        const v2h n3 = __builtin_amdgcn_cvt_pkrtz(s4 - s3, s3);
        struct alignas(16) H4 { v2h a, b, c, d; };
        *(H4*)(L + p * NDET + i) = H4{n0, n1, n2, n3};
    }
}

__device__ __forceinline__ void fb_visit(const v2h* __restrict__ L,
                                         float u, float& accA, float& accB) {
    const int   i0 = (int)u;
    const float fr = __builtin_amdgcn_fractf(u);
    const v2h wv = __builtin_amdgcn_cvt_pkrtz(fr, 1.0f);
    const v2h A = L[i0];
    const v2h B = L[i0 + NDET];
    accA = __builtin_amdgcn_fdot2(A, wv, accA, false);
    accB = __builtin_amdgcn_fdot2(B, wv, accB, false);
}

__global__ __launch_bounds__(512, 4) void backproject_fb_kernel(
    const float* __restrict__ proj, float* __restrict__ out)
{
    __shared__ alignas(16) v2h lds[2][2][2 * NDET];
    __shared__ v2f cs[NGRP];

    const int tid = threadIdx.x;
    if (tid < NGRP) {
        float s, c;
        sincosf((float)tid * DANG_F, &s, &c);
        cs[tid] = (v2f){c * RATIO_F, s * RATIO_F};
    }

    const int b    = blockIdx.z;
    const int lane = tid & 63;
    const int h    = (int)blockIdx.y * 8 + (tid >> 6);
    const int w0   = (int)blockIdx.x * 64 + lane;

    const float px = (float)w0 - (float)(IMGW - 1) * 0.5f;
    const float py = (float)(IMGH - 1) * 0.5f - (float)h;

    const float* __restrict__ sino = proj + (size_t)b * NVIEW * NDET;

    float a0 = 0.f, a1 = 0.f, a2 = 0.f, a3 = 0.f;
    float b0 = 0.f, b1 = 0.f, b2 = 0.f, b3 = 0.f;

    Stage s0 = {}, s1 = {};
    fb_load(sino, 0, tid, s0);
    fb_load(sino, 1, tid, s1);
    fb_write(lds[0][0], tid, s0);
    fb_write(lds[0][1], tid, s1);
    fb_load(sino, 2, tid, s0);
    fb_load(sino, 3, tid, s1);
    __syncthreads();

    for (int gg = 0; gg < NGRP; gg += 2) {
        const int buf = (gg >> 1) & 1;
#pragma unroll
        for (int sub = 0; sub < 2; ++sub) {
            const v2h* __restrict__ L = lds[buf][sub];
            const v2f t = cs[gg + sub];
            const v2f m1 = {t.x, -t.y};
            const v2f m2 = {t.y, t.x};
            const v2f pxv = {px, px};
            const v2f pyv = {py, py};
            const v2f gvec = __builtin_elementwise_fma(pxv, m1, pyv * m2);
            const v2f cc = {UCENTER, UCENTER};
            const v2f up = cc + gvec;
            const v2f um = cc - gvec;
            const v2f dd = {128.0f, 128.0f};
            const v2f dm = dd * m1;
            const v2f vp = up + dm;
            const v2f vm = um - dm;

            fb_visit(L, up.x, a0, a1);
            fb_visit(L, um.x, a2, a3);
            fb_visit(L, up.y, a3, a0);
            fb_visit(L, um.y, a1, a2);
            fb_visit(L, vp.x, b0, b1);
            fb_visit(L, vm.x, b2, b3);
            fb_visit(L, vp.y, b3, b0);
            fb_visit(L, vm.y, b1, b2);
        }
        if (gg < NGRP - 2) {
            fb_write(lds[buf ^ 1][0], tid, s0);
            fb_write(lds[buf ^ 1][1], tid, s1);
            if (gg < NGRP - 4) {
                fb_load(sino, gg + 4, tid, s0);
                fb_load(sino, gg + 5, tid, s1);
            }
            __syncthreads();
        }
    }

    float* __restrict__ o = out + (size_t)b * IMGH * IMGW;
    const int hm  = (IMGH - 1) - h;
    const int w1  = w0 + 128;
    const int wm0 = (IMGW - 1) - w0;
    const int wm1 = (IMGW - 1) - w1;
    o[h   * IMGW + w0 ] = a0 * DANG_F;
    o[wm0 * IMGW + h  ] = a1 * DANG_F;
    o[hm  * IMGW + wm0] = a2 * DANG_F;
    o[w0  * IMGW + hm ] = a3 * DANG_F;
    o[h   * IMGW + w1 ] = b0 * DANG_F;
    o[wm1 * IMGW + h  ] = b1 * DANG_F;
    o[hm  * IMGW + wm1] = b2 * DANG_F;
    o[w1  * IMGW + hm ] = b3 * DANG_F;
}

extern "C" void kernel_launch(void* const* d_in, const int* in_sizes, int n_in,
                              void* d_out, int out_size, void* d_ws, size_t ws_size,
                              hipStream_t stream) {
    const float* proj = (const float*)d_in[0];
    float* out = (float*)d_out;

    if (ws_size >= WS_BYTES) {
        E16* ws = (E16*)d_ws;
        prep_kernel<<<dim3(NITER, BATCH), 192, 0, stream>>>(proj, ws);
        backproject_dma_kernel<<<dim3(2, 32, BATCH), 512, 0, stream>>>(
            (const v8h*)ws, out);
    } else {
        backproject_fb_kernel<<<dim3(2, 32, BATCH), 512, 0, stream>>>(proj, out);
    }
}

// Round 4
// 144.572 us; speedup vs baseline: 1.3493x; 1.0008x over previous
//
#include <hip/hip_runtime.h>

// CT parallel-beam pixel-driven back-projection. Static geometry.
// R18: mirror-pair restructure (g <-> 180-g transpose symmetry): ws entry =
// 16 B {A_g(D,S), B_g(D,S), A_m(D,S), B_m(D,S)}; ONE ds_read_b128 gather
// feeds 4 fdot2. 728 gathers/thread, measured 18.0 cyc/gather (86.4 us).
// R19 (this round), three numerically-identical changes:
//  1. Bank-group XOR swizzle: entry j stored at slot j^((j>>3)&7) (prep
//     store side; DMA copies linearly so LDS inherits it; reads apply the
//     same XOR). Kills the du=8 same-bank-group collision lattice
//     (SQ_LDS_BANK_CONFLICT was 5.81M = ~2 cyc/read).
//  2. Double-buffer phases: 2 pair-iters per barrier (4x12KB ring = 2x24KB
//     double buffer), 90 -> 45 barriers.
//  3. XCD batch-affinity: flat block id & 7 = batch, so all 64 blocks of a
//     batch land on one XCD (linear dispatch round-robins XCDs) -> each
//     XCD-L2 fetches only its own batch's ws (FETCH was 34.6MB vs 8.85MB
//     ws). prep remapped identically so ws is L2-warm on the same XCD.
// Thread basing: fundamental domain of dihedral-8 (see R18 comments below).
// Fallback: if ws_size < needed, launch the proven R12 kernel (161 us).
#define BATCH 8
#define NVIEW 720
#define NPAIR 360
#define NGRP  180
#define NDET  736
#define IMGH  512
#define IMGW  512

#define DANG_F  ((float)(6.283185307179586 / 720.0))
#define RATIO_F ((float)(0.006641 / 0.0066))
#define UCENTER ((float)((NDET - 1) * 0.5))

#define PADDET 768        // entries per pair-iter (16 B each)
#define NITER  90         // 89 mirror pairs + 1 self-pair {0,90}
#define ITER_BYTES 12288  // 768 x 16 B
#define WS_BYTES ((size_t)BATCH * NITER * PADDET * 16)

// Bank-group swizzle: involution within each 8-entry block (64 B x 2 = one
// 128B bank wrap). Entry j's 16B row -> bank-group (j ^ (j>>3)) & 7.
#define SWZ(j) ((j) ^ (((j) >> 3) & 7))

typedef float  v2f __attribute__((ext_vector_type(2)));
typedef __fp16 v2h __attribute__((ext_vector_type(2)));
typedef __fp16 v8h __attribute__((ext_vector_type(8)));

struct alignas(16) E16 { v2h ag, bg, am, bm; };

// ---------------- prep kernel ----------------
// grid (90, 8) = 720 blocks; flat = y*90+x; batch = flat&7 (XCD affinity),
// pair p = flat>>3. Pair p: (g,m) = p<89 ? (p+1, 179-p) : (0, 90).
// Entry j: fused (D,S) fp16 for the 4 sub-arrays, S[j] = fwd[j]+rev[735-j],
// D = S[j+1]-S[j]. Overshoot taps land only in entry 735's D, never read
// (i0 <= 731); they stay within the batch's proj rows. Pad [736,768)
// unwritten (SWZ is 8-block-preserving, so written slots = [0,736) too).
__device__ __forceinline__ void fuse5(const float* __restrict__ fwd,
                                      const float* __restrict__ rev,
                                      int i, float s[5]) {
    const float4 f4 = *(const float4*)(fwd + i);
    const float  f1 = fwd[i + 4];
    const float4 r4 = *(const float4*)(rev + (732 - i));  // taps i..i+3=(w,z,y,x)
    const float  r1 = rev[731 - i];                       // tap i+4
    s[0] = f4.x + r4.w; s[1] = f4.y + r4.z; s[2] = f4.z + r4.y;
    s[3] = f4.w + r4.x; s[4] = f1 + r1;
}

__global__ __launch_bounds__(192) void prep_kernel(
    const float* __restrict__ proj, E16* __restrict__ ws)
{
    const int t = threadIdx.x;
    if (t >= 184) return;
    const int flat = (int)blockIdx.y * 90 + (int)blockIdx.x;
    const int b = flat & 7;
    const int p = flat >> 3;
    const int g = (p < 89) ? p + 1   : 0;
    const int m = (p < 89) ? 179 - p : 90;
    const int i = 4 * t;
    const float* __restrict__ base = proj + (size_t)b * NVIEW * NDET;
    float sAg[5], sBg[5], sAm[5], sBm[5];
    fuse5(base + (size_t)g * NDET,         base + (size_t)(g + 360) * NDET, i, sAg);
    fuse5(base + (size_t)(g + 180) * NDET, base + (size_t)(g + 540) * NDET, i, sBg);
    fuse5(base + (size_t)m * NDET,         base + (size_t)(m + 360) * NDET, i, sAm);
    fuse5(base + (size_t)(m + 180) * NDET, base + (size_t)(m + 540) * NDET, i, sBm);
    E16* __restrict__ dstb = ws + ((size_t)b * NITER + p) * PADDET;
#pragma unroll
    for (int k = 0; k < 4; ++k) {
        E16 e;
        e.ag = __builtin_amdgcn_cvt_pkrtz(sAg[k + 1] - sAg[k], sAg[k]);
        e.bg = __builtin_amdgcn_cvt_pkrtz(sBg[k + 1] - sBg[k], sBg[k]);
        e.am = __builtin_amdgcn_cvt_pkrtz(sAm[k + 1] - sAm[k], sAm[k]);
        e.bm = __builtin_amdgcn_cvt_pkrtz(sBm[k + 1] - sBm[k], sBm[k]);
        const int j = i + k;
        dstb[SWZ(j)] = e;        // store-side swizzle; 4 slots stay in one
    }                            // 64B-aligned run (SWZ flips low bits only)
}

// One b128 gather -> 4 fdot2 into 4 distinct accumulators.
#define VIS(Lp, u, r0, r1, r2, r3) do {                                      \
    const float uu_ = (u);                                                   \
    const int   ii_ = (int)uu_;                                              \
    const v2h wv_ = __builtin_amdgcn_cvt_pkrtz(                              \
        __builtin_amdgcn_fractf(uu_), 1.0f);                                 \
    const v8h E_ = (Lp)[SWZ(ii_)];                                           \
    r0 = __builtin_amdgcn_fdot2((v2h){E_[0], E_[1]}, wv_, r0, false);        \
    r1 = __builtin_amdgcn_fdot2((v2h){E_[2], E_[3]}, wv_, r1, false);        \
    r2 = __builtin_amdgcn_fdot2((v2h){E_[4], E_[5]}, wv_, r2, false);        \
    r3 = __builtin_amdgcn_fdot2((v2h){E_[6], E_[7]}, wv_, r3, false);        \
} while (0)

// Iter-89 visit: half-pair at elems [O,O+1] -> p0 AND p1; [O+2,O+3] -> q0,q1.
#define VIS2(Lp, O, u, p0, p1, q0, q1) do {                                  \
    const float uu_ = (u);                                                   \
    const int   ii_ = (int)uu_;                                              \
    const v2h wv_ = __builtin_amdgcn_cvt_pkrtz(                              \
        __builtin_amdgcn_fractf(uu_), 1.0f);                                 \
    const v8h E_ = (Lp)[SWZ(ii_)];                                           \
    const v2h ha_ = {E_[(O)], E_[(O) + 1]};                                  \
    const v2h hb_ = {E_[(O) + 2], E_[(O) + 3]};                              \
    p0 = __builtin_amdgcn_fdot2(ha_, wv_, p0, false);                        \
    p1 = __builtin_amdgcn_fdot2(ha_, wv_, p1, false);                        \
    q0 = __builtin_amdgcn_fdot2(hb_, wv_, q0, false);                        \
    q1 = __builtin_amdgcn_fdot2(hb_, wv_, q1, false);                        \
} while (0)

// Iter-89 diag: one target per half.
#define VIS1(Lp, O, u, p0, q0) do {                                          \
    const float uu_ = (u);                                                   \
    const int   ii_ = (int)uu_;                                              \
    const v2h wv_ = __builtin_amdgcn_cvt_pkrtz(                              \
        __builtin_amdgcn_fractf(uu_), 1.0f);                                 \
    const v8h E_ = (Lp)[SWZ(ii_)];                                           \
    p0 = __builtin_amdgcn_fdot2((v2h){E_[(O)], E_[(O) + 1]}, wv_, p0, false);\
    q0 = __builtin_amdgcn_fdot2((v2h){E_[(O) + 2], E_[(O) + 3]}, wv_, q0,    \
                                false);                                      \
} while (0)

// ---------------- main kernel (DMA path) ----------------
// 512 threads = 8 waves; grid (2, 32, BATCH) = 512 blocks = 2/CU; flat
// block id & 7 = batch (XCD affinity), tile = flat>>3 -> (tile>>1)=h-tile,
// (tile&1)=w-half. Phase k (k=0..43): issue(2k+2), issue(2k+3) -> compute
// iters 2k, 2k+1 -> barrier. 4x12KB slots = double-buffered 24KB halves:
// phase k reads pair {2k&3,(2k+1)&3}, DMA writes the other pair; the
// end-of-phase barrier's vmcnt(0) drain waits on DMAs aged by TWO groups
// (~4600 cyc) -> free. 45 barriers (was 90). Iter 89 = self-mirrored
// groups {0,90}, slot 89&3 = 1, computed after the loop.
// |g1|,|g2| <= 363.6 < 367.5 -> i0 in [3,731], +1 tap <= 732 < 736.
// R(row,col) = (511-col, row); centered R(x,y) = (-y, x).
__global__ __launch_bounds__(512, 4) void backproject_dma_kernel(
    const v8h* __restrict__ ws, float* __restrict__ out)
{
    __shared__ alignas(16) v8h lds4[4][PADDET];  // 4 x 12288 B ring
    __shared__ v2f cs[NGRP];

    const int tid  = threadIdx.x;
    const int wave = tid >> 6;
    const int lane = tid & 63;

    if (tid < NGRP) {
        float s, c;
        sincosf((float)tid * DANG_F, &s, &c);
        cs[tid] = (v2f){c * RATIO_F, s * RATIO_F};   // sealed by 1st barrier
    }

    const int flat = ((int)blockIdx.z * 32 + (int)blockIdx.y) * 2
                     + (int)blockIdx.x;
    const int b    = flat & 7;                           // batch -> XCD
    const int tile = flat >> 3;                          // [0, 64)
    const int h = (tile >> 1) * 8 + wave;                // [0, 256)
    const int w = (tile & 1) * 64 + lane;                // [0, 128)

    const bool dg = (w == h);                            // diagonal lane
    const bool rm = (w > h);                             // remapped lane
    const int  H  = rm ? 255 - h : h;
    const int  W  = rm ? 255 - w : w;

    const float px  = (float)W - 255.5f;
    const float py  = 255.5f - (float)H;
    // P2: normal/remap -> swap (k-addresses); diag -> base2 = (255-d,255-d).
    const float px2 = dg ? (-0.5f - (float)W) : py;
    const float py2 = dg ? ( 0.5f + (float)H) : px;

    const char* __restrict__ wsb =
        (const char*)(ws + (size_t)b * NITER * PADDET);

    float A0 = 0.f, A1 = 0.f, A2 = 0.f, A3 = 0.f;
    float B0 = 0.f, B1 = 0.f, B2 = 0.f, B3 = 0.f;
    float X0 = 0.f, X1 = 0.f, X2 = 0.f, X3 = 0.f;
    float Y0 = 0.f, Y1 = 0.f, Y2 = 0.f, Y3 = 0.f;

    auto issue = [&](int p) {
        const char* g0 = wsb + (size_t)p * ITER_BYTES;
        char* l0 = (char*)&lds4[p & 3][0];
        __builtin_amdgcn_global_load_lds(
            (const __attribute__((address_space(1))) void*)
                (g0 + wave * 1024 + lane * 16),
            (__attribute__((address_space(3))) void*)(l0 + wave * 1024),
            16, 0, 0);
        if (wave < 4) {
            const int s = 8 + wave;
            __builtin_amdgcn_global_load_lds(
                (const __attribute__((address_space(1))) void*)
                    (g0 + s * 1024 + lane * 16),
                (__attribute__((address_space(3))) void*)(l0 + s * 1024),
                16, 0, 0);
        }
    };

    const v2f cc = {UCENTER, UCENTER};
    auto groups = [&](int p) {
        const v8h* __restrict__ L = &lds4[p & 3][0];
        const v2f t  = cs[p + 1];                // group g = p+1
        const v2f m1 = {t.x, -t.y};
        const v2f m2 = {t.y, t.x};
        // (g1,g2) for P1; (g1b,g2b) for P2 — all at theta_g.
        const v2f gA = __builtin_elementwise_fma(
            (v2f){px, px}, m1, (v2f){py, py} * m2);
        const v2f gB = __builtin_elementwise_fma(
            (v2f){px2, px2}, m1, (v2f){py2, py2} * m2);
        const v2f upA = cc + gA, umA = cc - gA;
        const v2f upB = cc + gB, umB = cc - gB;
        VIS(L, upA.x, A0, A1, X2, X3);   // C+g1
        VIS(L, umA.x, A2, A3, X0, X1);   // C-g1
        VIS(L, upA.y, A3, A0, X3, X0);   // C+g2
        VIS(L, umA.y, A1, A2, X1, X2);   // C-g2
        VIS(L, upB.x, B2, B3, Y0, Y1);   // C+g1b
        VIS(L, umB.x, B0, B1, Y2, Y3);   // C-g1b
        VIS(L, upB.y, B1, B2, Y1, Y2);   // C+g2b
        VIS(L, umB.y, B3, B0, Y3, Y0);   // C-g2b
    };

    issue(0);
    issue(1);
    __syncthreads();   // drains issues 0,1 + seals cs[]

    for (int k = 0; k < 44; ++k) {
        issue(2 * k + 2);
        issue(2 * k + 3);
        groups(2 * k);
        groups(2 * k + 1);
        __syncthreads();   // drain aged DMA (2 groups old); RW separation
    }
    groups(88);            // iter 88 (pair (89,91)), slot 0

    // -------- iter 89: self-mirrored groups {0, 90} (slot 89&3 = 1) -----
    {
        const v8h* __restrict__ L = &lds4[1][0];
        const v2f t0 = cs[0], t45 = cs[90];
        if (!dg) {
            // theta=0 (halves 0,1 = A0/B0 arrays), P1 addresses; each value
            // serves own-orbit AND transposed-orbit pixel (same column/row).
            const float g1 = px * t0.x + py * t0.y;
            const float g2 = -px * t0.y + py * t0.x;
            VIS2(L, 0, UCENTER + g1, A0, X1, A1, X2);
            VIS2(L, 0, UCENTER - g1, A2, X3, A3, X0);
            VIS2(L, 0, UCENTER + g2, A3, X2, A0, X3);
            VIS2(L, 0, UCENTER - g2, A1, X0, A2, X1);
            // theta=45 (halves 4..7 = A90/B90 arrays).
            const float h1 = px * t45.x + py * t45.y;
            const float h2 = -px * t45.y + py * t45.x;
            VIS2(L, 4, UCENTER + h1, A0, X2, A1, X3);
            VIS2(L, 4, UCENTER - h1, A2, X0, A3, X1);
            VIS2(L, 4, UCENTER + h2, A3, X3, A0, X0);
            VIS2(L, 4, UCENTER - h2, A1, X1, A2, X2);
        } else {
            // Diagonal lanes: base1 = (d,d) into A-bank; base2 into B-bank
            // (relabeled b_j = R^(j+2)(base2)).
            const float g1  = px * t0.x + py * t0.y;    // theta0, base1
            const float g1b = px2 * t0.x + py2 * t0.y;  // theta0, base2
            VIS2(L, 0, UCENTER + g1,  A0, A1, A1, A2);
            VIS2(L, 0, UCENTER - g1,  A2, A3, A0, A3);
            VIS2(L, 0, UCENTER + g1b, B2, B3, B3, B0);
            VIS2(L, 0, UCENTER - g1b, B0, B1, B2, B1);
            // theta=45: P1-orbit sums pi_x+pi_y in {0, +-2px}; base2 same.
            {   // u = UCENTER: serves base1 {a0,a2}/{a1,a3} and base2.
                const v2h wv_ = __builtin_amdgcn_cvt_pkrtz(0.5f, 1.0f);
                const v8h E_ = L[SWZ(367)];      // (int)UCENTER = 367
                const v2h ha_ = {E_[4], E_[5]};
                const v2h hb_ = {E_[6], E_[7]};
                A0 = __builtin_amdgcn_fdot2(ha_, wv_, A0, false);
                A2 = __builtin_amdgcn_fdot2(ha_, wv_, A2, false);
                B2 = __builtin_amdgcn_fdot2(ha_, wv_, B2, false);
                B0 = __builtin_amdgcn_fdot2(ha_, wv_, B0, false);
                A1 = __builtin_amdgcn_fdot2(hb_, wv_, A1, false);
                A3 = __builtin_amdgcn_fdot2(hb_, wv_, A3, false);
                B3 = __builtin_amdgcn_fdot2(hb_, wv_, B3, false);
                B1 = __builtin_amdgcn_fdot2(hb_, wv_, B1, false);
            }
            const float e1 = (px + px) * t45.x;
            const float e2 = (px2 + px2) * t45.x;
            VIS1(L, 4, UCENTER + e1, A1, A2);
            VIS1(L, 4, UCENTER - e1, A3, A0);
            VIS1(L, 4, UCENTER + e2, B3, B0);
            VIS1(L, 4, UCENTER - e2, B1, B2);
        }
    }

    // -------- write: 8 pixels, two R-orbits --------
    const float aE0 = dg ? X0 : Y0, aE1 = dg ? X1 : Y1;
    const float aE2 = dg ? X2 : Y2, aE3 = dg ? X3 : Y3;
    const float bE0 = dg ? Y0 : X0, bE1 = dg ? Y1 : X1;
    const float bE2 = dg ? Y2 : X2, bE3 = dg ? Y3 : X3;
    const float a0 = (A0 + aE0) * DANG_F, a1 = (A1 + aE1) * DANG_F;
    const float a2 = (A2 + aE2) * DANG_F, a3 = (A3 + aE3) * DANG_F;
    const float b0 = (B0 + bE0) * DANG_F, b1 = (B1 + bE1) * DANG_F;
    const float b2 = (B2 + bE2) * DANG_F, b3 = (B3 + bE3) * DANG_F;

    float* __restrict__ o = out + (size_t)b * IMGH * IMGW;
    const int Qr = dg ? 256 + H : W;
    const int Qc = dg ? 256 + W : H;
    o[H * IMGW + W]                         = a0;
    o[(511 - W) * IMGW + H]                 = a1;
    o[(511 - H) * IMGW + (511 - W)]         = a2;
    o[W * IMGW + (511 - H)]                 = a3;
    o[Qr * IMGW + Qc]                       = b0;
    o[(511 - Qc) * IMGW + Qr]               = b1;
    o[(511 - Qr) * IMGW + (511 - Qc)]       = b2;
    o[Qc * IMGW + (511 - Qr)]               = b3;
}

// ---------------- fallback (R12, proven 161 us) ----------------
struct Stage { float4 f4, r4; float f1, r1; };

__device__ __forceinline__ void fb_load(const float* __restrict__ sino,
                                        int k, int t, Stage& S) {
    if (t < 368) {
        const int p  = (t >= 184);
        const int i  = 4 * (t - 184 * p);
        const int vf = k + 180 * p;
        const float* __restrict__ fwd = sino + vf * NDET;
        const float* __restrict__ rev = sino + (vf + NPAIR) * NDET;
        S.f4 = *(const float4*)(fwd + i);
        S.f1 = fwd[i + 4];
        S.r4 = *(const float4*)(rev + (732 - i));
        S.r1 = rev[731 - i];
    }
}

__device__ __forceinline__ void fb_write(v2h* __restrict__ L, int t,
                                         const Stage& S) {
    if (t < 368) {
        const int p = (t >= 184);
        const int i = 4 * (t - 184 * p);
        const float s0 = S.f4.x + S.r4.w;
        const float s1 = S.f4.y + S.r4.z;
        const float s2 = S.f4.z + S.r4.y;
        const float s3 = S.f4.w + S.r4.x;
        const float s4 = S.f1 + S.r1;
        const v2h n0 = __builtin_amdgcn_cvt_pkrtz(s1 - s0, s0);
        const v2h n1 = __builtin_amdgcn_cvt_pkrtz(s2 - s1, s1);
        const v2h n2 = __builtin_amdgcn_cvt_pkrtz(s3 - s2, s2);
        const v2h n3 = __builtin_amdgcn_cvt_pkrtz(s4 - s3, s3);
        struct alignas(16) H4 { v2h a, b, c, d; };
        *(H4*)(L + p * NDET + i) = H4{n0, n1, n2, n3};
    }
}

__device__ __forceinline__ void fb_visit(const v2h* __restrict__ L,
                                         float u, float& accA, float& accB) {
    const int   i0 = (int)u;
    const float fr = __builtin_amdgcn_fractf(u);
    const v2h wv = __builtin_amdgcn_cvt_pkrtz(fr, 1.0f);
    const v2h A = L[i0];
    const v2h B = L[i0 + NDET];
    accA = __builtin_amdgcn_fdot2(A, wv, accA, false);
    accB = __builtin_amdgcn_fdot2(B, wv, accB, false);
}

__global__ __launch_bounds__(512, 4) void backproject_fb_kernel(
    const float* __restrict__ proj, float* __restrict__ out)
{
    __shared__ alignas(16) v2h lds[2][2][2 * NDET];
    __shared__ v2f cs[NGRP];

    const int tid = threadIdx.x;
    if (tid < NGRP) {
        float s, c;
        sincosf((float)tid * DANG_F, &s, &c);
        cs[tid] = (v2f){c * RATIO_F, s * RATIO_F};
    }

    const int b    = blockIdx.z;
    const int lane = tid & 63;
    const int h    = (int)blockIdx.y * 8 + (tid >> 6);
    const int w0   = (int)blockIdx.x * 64 + lane;

    const float px = (float)w0 - (float)(IMGW - 1) * 0.5f;
    const float py = (float)(IMGH - 1) * 0.5f - (float)h;

    const float* __restrict__ sino = proj + (size_t)b * NVIEW * NDET;

    float a0 = 0.f, a1 = 0.f, a2 = 0.f, a3 = 0.f;
    float b0 = 0.f, b1 = 0.f, b2 = 0.f, b3 = 0.f;

    Stage s0 = {}, s1 = {};
    fb_load(sino, 0, tid, s0);
    fb_load(sino, 1, tid, s1);
    fb_write(lds[0][0], tid, s0);
    fb_write(lds[0][1], tid, s1);
    fb_load(sino, 2, tid, s0);
    fb_load(sino, 3, tid, s1);
    __syncthreads();

    for (int gg = 0; gg < NGRP; gg += 2) {
        const int buf = (gg >> 1) & 1;
#pragma unroll
        for (int sub = 0; sub < 2; ++sub) {
            const v2h* __restrict__ L = lds[buf][sub];
            const v2f t = cs[gg + sub];
            const v2f m1 = {t.x, -t.y};
            const v2f m2 = {t.y, t.x};
            const v2f pxv = {px, px};
            const v2f pyv = {py, py};
            const v2f gvec = __builtin_elementwise_fma(pxv, m1, pyv * m2);
            const v2f cc = {UCENTER, UCENTER};
            const v2f up = cc + gvec;
            const v2f um = cc - gvec;
            const v2f dd = {128.0f, 128.0f};
            const v2f dm = dd * m1;
            const v2f vp = up + dm;
            const v2f vm = um - dm;

            fb_visit(L, up.x, a0, a1);
            fb_visit(L, um.x, a2, a3);
            fb_visit(L, up.y, a3, a0);
            fb_visit(L, um.y, a1, a2);
            fb_visit(L, vp.x, b0, b1);
            fb_visit(L, vm.x, b2, b3);
            fb_visit(L, vp.y, b3, b0);
            fb_visit(L, vm.y, b1, b2);
        }
        if (gg < NGRP - 2) {
            fb_write(lds[buf ^ 1][0], tid, s0);
            fb_write(lds[buf ^ 1][1], tid, s1);
            if (gg < NGRP - 4) {
                fb_load(sino, gg + 4, tid, s0);
                fb_load(sino, gg + 5, tid, s1);
            }
            __syncthreads();
        }
    }

    float* __restrict__ o = out + (size_t)b * IMGH * IMGW;
    const int hm  = (IMGH - 1) - h;
    const int w1  = w0 + 128;
    const int wm0 = (IMGW - 1) - w0;
    const int wm1 = (IMGW - 1) - w1;
    o[h   * IMGW + w0 ] = a0 * DANG_F;
    o[wm0 * IMGW + h  ] = a1 * DANG_F;
    o[hm  * IMGW + wm0] = a2 * DANG_F;
    o[w0  * IMGW + hm ] = a3 * DANG_F;
    o[h   * IMGW + w1 ] = b0 * DANG_F;
    o[wm1 * IMGW + h  ] = b1 * DANG_F;
    o[hm  * IMGW + wm1] = b2 * DANG_F;
    o[w1  * IMGW + hm ] = b3 * DANG_F;
}

extern "C" void kernel_launch(void* const* d_in, const int* in_sizes, int n_in,
                              void* d_out, int out_size, void* d_ws, size_t ws_size,
                              hipStream_t stream) {
    const float* proj = (const float*)d_in[0];
    float* out = (float*)d_out;

    if (ws_size >= WS_BYTES) {
        E16* ws = (E16*)d_ws;
        prep_kernel<<<dim3(90, BATCH), 192, 0, stream>>>(proj, ws);
        backproject_dma_kernel<<<dim3(2, 32, BATCH), 512, 0, stream>>>(
            (const v8h*)ws, out);
    } else {
        backproject_fb_kernel<<<dim3(2, 32, BATCH), 512, 0, stream>>>(proj, out);
    }
}